// Round 20
// baseline (39.560 us; speedup 1.0000x reference)
//
#include <hip/hip_runtime.h>
#include <hip/hip_bf16.h>

#define B 32
#define T 8192
#define H 128

typedef __attribute__((ext_vector_type(8)))  short short8_t;   // 8 bf16 = 4 VGPR
typedef __attribute__((ext_vector_type(16))) float f32x16;     // MFMA 32x32 acc

static __device__ __forceinline__ unsigned fbits(float x) { return __builtin_bit_cast(unsigned, x); }
static __device__ __forceinline__ float bfloat(unsigned u) { return __builtin_bit_cast(float, u); }

// split float4 -> 2 u32 of bf16-hi (truncated) + 2 u32 of bf16-lo (exact rem)
static __device__ __forceinline__ void pack4(const float4 f,
                                             unsigned& hi0, unsigned& hi1,
                                             unsigned& lo0, unsigned& lo1) {
    const unsigned u0 = fbits(f.x), u1 = fbits(f.y), u2 = fbits(f.z), u3 = fbits(f.w);
    const unsigned h0 = u0 & 0xffff0000u, h1 = u1 & 0xffff0000u;
    const unsigned h2 = u2 & 0xffff0000u, h3 = u3 & 0xffff0000u;
    const float r0 = f.x - bfloat(h0), r1 = f.y - bfloat(h1);
    const float r2 = f.z - bfloat(h2), r3 = f.w - bfloat(h3);
    hi0 = (u0 >> 16) | h1;                      hi1 = (u2 >> 16) | h3;
    lo0 = (fbits(r0) >> 16) | (fbits(r1) & 0xffff0000u);
    lo1 = (fbits(r2) >> 16) | (fbits(r3) & 0xffff0000u);
}

// hi-only pack (enc staging; x-lo dropped since r17)
static __device__ __forceinline__ void pack4hi(const float4 f,
                                               unsigned& hi0, unsigned& hi1) {
    const unsigned u0 = fbits(f.x), u1 = fbits(f.y), u2 = fbits(f.z), u3 = fbits(f.w);
    hi0 = (u0 >> 16) | (u1 & 0xffff0000u);
    hi1 = (u2 >> 16) | (u3 & 0xffff0000u);
}

// pack a 16-float span (two float4) into hi + lo short8 fragments
static __device__ __forceinline__ void pack_frag(const float4 a, const float4 b,
                                                 short8_t& hi, short8_t& lo) {
    union { short8_t v8; unsigned w[4]; } ph, pl;
    unsigned h0, h1, l0, l1;
    pack4(a, h0, h1, l0, l1); ph.w[0] = h0; ph.w[1] = h1; pl.w[0] = l0; pl.w[1] = l1;
    pack4(b, h0, h1, l0, l1); ph.w[2] = h0; ph.w[3] = h1; pl.w[2] = l0; pl.w[3] = l1;
    hi = ph.v8; lo = pl.v8;
}

// ws layout: [80K,144K) sm partials (offsets kept stable across rounds)
#define PART_OFF 81920

// ---------------------------------------------------------------------------
// Kernel 1: scores via MFMA — FULLY FUSED (k_prep deleted).
//
// Prologue now does everything in-block:
//  - W2 frags packed straight from W_attn cols [H,2H) (L2/L3-hot, 256 B/lane).
//  - u computed via the SAME MFMA path: u[h][b] = b_attn + W1·hidden^T has
//    the main loop's exact shape, and the MFMA D-layout (col=l31=b,
//    row=j+8*r4+4*kh) is precisely what the C-init consumes -> bias C-init,
//    8 s-steps x 3-term hi/lo MFMA (W1 x hidden frags) -> uacc; each round
//    inits acc = uacc. (u err ~1e-5 rel, prob-level ~1e-6 — negligible.)
// Saves k_prep (~2-3 us) + one launch gap (~2 us) at ~0.5 us prologue cost.
//
// Evidence ledger (unchanged): pre-pack enc at stage time (r14 +22%), x-lo
// dropped (r17 +15%), ragged stage guard + strided tiles (r19, absmax-
// preserving), fused sm partials (r18), (512,2) + W2-in-regs (r15: (512,4)
// regresses), rotation swizzle (r9+), T14 double-buffer (r11-r13 neutral).
// ---------------------------------------------------------------------------
__global__ __launch_bounds__(512, 2) void k_scores_mfma(
    const float* __restrict__ enc,                 // [T*B][H]
    const float* __restrict__ hidden,              // [B][H]
    const float* __restrict__ b_attn,              // [H]
    const float* __restrict__ W_attn,              // [H][2H]
    const float* __restrict__ v,                   // [H]
    const int* __restrict__ len_seq,               // [B]
    float* __restrict__ scores,                    // [B][T]
    float* __restrict__ part)                      // [B][256] x (M,S)
{
    __shared__ uint2 hb[2][2048];                  // hi planes, 2 x 16 KB
    __shared__ float cbuf[2][2][4][32];            // [parity][tsel][mtile][b]
    __shared__ float pm[2][32], ps[2][32];         // partial fold buffers

    const int tid   = threadIdx.x;
    const int lane  = tid & 63;
    const int wid   = tid >> 6;     // 0..7
    const int tsel  = wid >> 2;     // 0..1 : which t of the tile
    const int mtile = wid & 3;      // 0..3 : 32-row h-tile
    const int l31   = lane & 31;
    const int kh    = lane >> 5;

    // staging role: 8 threads per tile-row, 4 float4 each
    const int srow = tid >> 3;      // tile row 0..63 (t-local = srow>>5, b = srow&31)
    const int st8  = tid & 7;

    const int blk = blockIdx.x;                 // strided tiles: tile(q) = blk + 256q
    const float4* enc4 = (const float4*)enc;    // 32 x 16B units per row

    // stage-guard constants: row's t for tile p = 2*(blk+256p) + (srow>>5)
    const int lenrow = len_seq[srow & 31];
    const int tsb    = 2 * blk + (srow >> 5);   // t of this row at p=0 (+512 per p)

    // ---- W2 fragments packed from W_attn cols [H,2H) -> 64 VGPRs ----
    short8_t w2hi[8], w2lo[8];
    {
        const int h = mtile * 32 + l31;
        const float* wrow = W_attn + (size_t)h * (2 * H) + H;
#pragma unroll
        for (int s = 0; s < 8; ++s) {
            const int k0 = s * 16 + kh * 8;
            const float4 a = *(const float4*)(wrow + k0);
            const float4 b = *(const float4*)(wrow + k0 + 4);
            pack_frag(a, b, w2hi[s], w2lo[s]);
        }
    }

    // ---- u via MFMA: uacc[h][b] = b_attn[h] + W1[h,:].hidden[b,:] ----
    f32x16 uacc;
    {
#pragma unroll
        for (int r4 = 0; r4 < 4; ++r4) {        // bias C-init (row layout match)
            const float4 bb4 = *(const float4*)(b_attn + mtile * 32 + r4 * 8 + kh * 4);
            uacc[4 * r4 + 0] = bb4.x; uacc[4 * r4 + 1] = bb4.y;
            uacc[4 * r4 + 2] = bb4.z; uacc[4 * r4 + 3] = bb4.w;
        }
        const int h = mtile * 32 + l31;
        const float* wrow = W_attn + (size_t)h * (2 * H);     // W1 = cols [0,H)
        const float* xrow = hidden + l31 * H;                 // lane's own b-row
#pragma unroll
        for (int s = 0; s < 8; ++s) {
            const int k0 = s * 16 + kh * 8;
            short8_t w1h, w1l, xh, xl;
            pack_frag(*(const float4*)(wrow + k0), *(const float4*)(wrow + k0 + 4), w1h, w1l);
            pack_frag(*(const float4*)(xrow + k0), *(const float4*)(xrow + k0 + 4), xh, xl);
            uacc = __builtin_amdgcn_mfma_f32_32x32x16_bf16(w1h, xh, uacc, 0, 0, 0);
            uacc = __builtin_amdgcn_mfma_f32_32x32x16_bf16(w1l, xh, uacc, 0, 0, 0);
            uacc = __builtin_amdgcn_mfma_f32_32x32x16_bf16(w1h, xl, uacc, 0, 0, 0);
        }
    }

    float4 vv[4];
#pragma unroll
    for (int r4 = 0; r4 < 4; ++r4)
        vv[r4] = *(const float4*)(v + mtile * 32 + r4 * 8 + kh * 4);
    const int lenb = len_seq[l31];              // used by flush threads

    // ---- prologue: tile 0 -> buf0 (guarded); issue tile-1 loads (guarded) ----
    float4 stg[4];
    {
        if (tsb < lenrow) {                     // tile 0 row valid
            const float4* gs = enc4 + ((size_t)(2 * blk) * 32 + srow) * 32;
#pragma unroll
            for (int i = 0; i < 4; ++i) stg[i] = gs[st8 + 8 * i];
#pragma unroll
            for (int i = 0; i < 4; ++i) {
                unsigned hi0, hi1;
                pack4hi(stg[i], hi0, hi1);
                const int p16 = st8 + 8 * i;
                const int idx = srow * 32 + (((p16 >> 1) + srow) & 15) * 2 + (p16 & 1);
                hb[0][idx] = make_uint2(hi0, hi1);
            }
        }
        if (tsb + 512 < lenrow) {               // tile 1 row valid
            const float4* gs1 = enc4 + ((size_t)(2 * (blk + 256)) * 32 + srow) * 32;
#pragma unroll
            for (int i = 0; i < 4; ++i) stg[i] = gs1[st8 + 8 * i];
        }
    }
    __syncthreads();   // buf0 ready

    const int rrow  = tsel * 32 + l31;          // reader's tile row
    const int rbase = rrow * 32;                // uint2 base of that row

    float m_run = -1e30f, s_run = 0.0f;         // online softmax partial

#pragma unroll 1
    for (int q = 0; q < 16; ++q) {
        const int cur = q & 1, nxt = cur ^ 1;

        // ---- pack+write tile q+1 (in stg) into buf[nxt]; guard matches the
        //      load guard that filled stg (same formula, p = q+1) ----
        if (q < 15 && tsb + 512 * (q + 1) < lenrow) {
#pragma unroll
            for (int i = 0; i < 4; ++i) {
                unsigned hi0, hi1;
                pack4hi(stg[i], hi0, hi1);
                const int p16 = st8 + 8 * i;
                const int idx = srow * 32 + (((p16 >> 1) + srow) & 15) * 2 + (p16 & 1);
                hb[nxt][idx] = make_uint2(hi0, hi1);
            }
        }
        // ---- issue tile q+2 loads (guarded; latency hides under compute) ----
        if (q < 14 && tsb + 512 * (q + 2) < lenrow) {
            const float4* gs = enc4 + ((size_t)(2 * (blk + 256 * (q + 2))) * 32 + srow) * 32;
#pragma unroll
            for (int i = 0; i < 4; ++i) stg[i] = gs[st8 + 8 * i];
        }

        // ---- compute own (t, mtile) from buf[cur]: 1 ds_read + 2 MFMA /s ----
        f32x16 acc = uacc;                      // C-init = u (layout match)

#pragma unroll
        for (int s = 0; s < 8; ++s) {
            const int slot = (2 * s + kh + l31) & 15;       // (unit+row)&15
            const short8_t bh = *(const short8_t*)&hb[cur][rbase + slot * 2];
            acc = __builtin_amdgcn_mfma_f32_32x32x16_bf16(w2hi[s], bh, acc, 0, 0, 0);
            acc = __builtin_amdgcn_mfma_f32_32x32x16_bf16(w2lo[s], bh, acc, 0, 0, 0);
        }

        // ---- partial score over this wave's 32 h-rows ----
        float psum = 0.f;
#pragma unroll
        for (int r4 = 0; r4 < 4; ++r4) {
            psum = fmaf(fmaxf(acc[4 * r4 + 0], 0.f), vv[r4].x, psum);
            psum = fmaf(fmaxf(acc[4 * r4 + 1], 0.f), vv[r4].y, psum);
            psum = fmaf(fmaxf(acc[4 * r4 + 2], 0.f), vv[r4].z, psum);
            psum = fmaf(fmaxf(acc[4 * r4 + 3], 0.f), vv[r4].w, psum);
        }
        psum += __shfl_xor(psum, 32);   // collapse kh halves; lanes<32 hold b

        if (lane < 32) cbuf[cur][tsel][mtile][l31] = psum;

        __syncthreads();   // buf[nxt] written, cbuf[cur] visible, buf[cur] free

        if (mtile == 0 && lane < 32) {
            const float r = cbuf[cur][tsel][0][l31] + cbuf[cur][tsel][1][l31]
                          + cbuf[cur][tsel][2][l31] + cbuf[cur][tsel][3][l31];
            const int t = 2 * (blk + 256 * q) + tsel;
            scores[(size_t)l31 * T + t] = r;
            if (t < lenb) {                    // online (max, exp-sum) update
                const float m_new = fmaxf(m_run, r);
                s_run = s_run * __expf(m_run - m_new) + __expf(r - m_new);
                m_run = m_new;
            }
        }
    }

    // ---- fold tsel halves, one (M,S) per (b, block) ----
    if (mtile == 0 && lane < 32) { pm[tsel][l31] = m_run; ps[tsel][l31] = s_run; }
    __syncthreads();
    if (tid < 32) {
        const float m0 = pm[0][tid], m1 = pm[1][tid];
        const float s0 = ps[0][tid], s1 = ps[1][tid];
        const float M = fmaxf(m0, m1);
        const float S = s0 * __expf(m0 - M) + s1 * __expf(m1 - M);
        *(float2*)&part[((size_t)tid * 256 + blk) * 2] = make_float2(M, S);
    }
}

// ---------------------------------------------------------------------------
// Kernel 2: wide softmax finish — fold 256 per-block partials per b, then
// rescale in place. 256 blocks (8 chunks x 32 b) x 256 threads x 4 elems.
// ---------------------------------------------------------------------------
__global__ __launch_bounds__(256) void k_sm_final(
    float* __restrict__ out,            // [B][T] raw scores -> probs
    const int* __restrict__ len_seq,
    const float* __restrict__ part)     // [B][256] x (M,S)
{
    const int b    = blockIdx.x >> 3;
    const int c    = blockIdx.x & 7;
    const int tid  = threadIdx.x;
    const int lane = tid & 63;
    const int wid  = tid >> 6;
    const int len  = len_seq[b];

    __shared__ float rm[4], rs[4];

    float2 p = *(const float2*)&part[((size_t)b * 256 + tid) * 2];
    float m = p.x, s = p.y;
#pragma unroll
    for (int off = 32; off >= 1; off >>= 1) {
        const float m2 = __shfl_xor(m, off);
        const float s2 = __shfl_xor(s, off);
        const float M = fmaxf(m, m2);
        s = s * __expf(m - M) + s2 * __expf(m2 - M);
        m = M;
    }
    if (lane == 0) { rm[wid] = m; rs[wid] = s; }
    __syncthreads();
    const float M = fmaxf(fmaxf(rm[0], rm[1]), fmaxf(rm[2], rm[3]));
    const float S = rs[0] * __expf(rm[0] - M) + rs[1] * __expf(rm[1] - M)
                  + rs[2] * __expf(rm[2] - M) + rs[3] * __expf(rm[3] - M);
    const float inv = 1.0f / S;

    float* srow = out + (size_t)b * T + c * 1024;
#pragma unroll
    for (int i = 0; i < 4; ++i) {
        const int tl = tid + i * 256;
        const int t  = c * 1024 + tl;
        const float x = srow[tl];
        srow[tl] = (t < len) ? __expf(x - M) * inv : 0.0f;
    }
}

// ---------------------------------------------------------------------------
extern "C" void kernel_launch(void* const* d_in, const int* in_sizes, int n_in,
                              void* d_out, int out_size, void* d_ws, size_t ws_size,
                              hipStream_t stream) {
    const float* hidden = (const float*)d_in[0];
    const float* enc    = (const float*)d_in[1];
    const int*   len    = (const int*)d_in[2];
    const float* W      = (const float*)d_in[3];
    const float* bb     = (const float*)d_in[4];
    const float* v      = (const float*)d_in[5];

    float* out  = (float*)d_out;
    float* part = (float*)((char*)d_ws + PART_OFF);                 // 64 KB

    k_scores_mfma<<<256, 512, 0, stream>>>(enc, hidden, bb, W, v, len, out, part);
    k_sm_final<<<B * 8, 256, 0, stream>>>(out, len, part);
}

// Round 21
// 34.578 us; speedup vs baseline: 1.1441x; 1.1441x over previous
//
#include <hip/hip_runtime.h>
#include <hip/hip_bf16.h>

#define B 32
#define T 8192
#define H 128

typedef __attribute__((ext_vector_type(8)))  short short8_t;   // 8 bf16 = 4 VGPR
typedef __attribute__((ext_vector_type(16))) float f32x16;     // MFMA 32x32 acc

static __device__ __forceinline__ unsigned fbits(float x) { return __builtin_bit_cast(unsigned, x); }
static __device__ __forceinline__ float bfloat(unsigned u) { return __builtin_bit_cast(float, u); }

// pack float4 -> 2 u32 of bf16-hi (truncated). x-lo DROPPED (r17: precision
// budget -> LDS bandwidth; absmax 3.05e-5 vs 1.495e-4 threshold).
static __device__ __forceinline__ void pack4hi(const float4 f,
                                               unsigned& hi0, unsigned& hi1) {
    const unsigned u0 = fbits(f.x), u1 = fbits(f.y), u2 = fbits(f.z), u3 = fbits(f.w);
    hi0 = (u0 >> 16) | (u1 & 0xffff0000u);
    hi1 = (u2 >> 16) | (u3 & 0xffff0000u);
}

// ws layout: [0,16K) u fp32 ; [16K,80K) W2 hi|lo frags ; [80K,144K) sm partials
#define WPK_OFF  16384
#define PART_OFF 81920

// ---------------------------------------------------------------------------
// Kernel 1 (merged prep): blocks 0..31 -> u[b][h]; blocks 32..39 -> pack W2.
// (r20 tried fusing this into k_scores: the per-block redundant W-pack
//  prologue cost ~5 us > the ~2-3 us launch saving. Keep it separate.)
// ---------------------------------------------------------------------------
__global__ void k_prep(const float* __restrict__ hidden,
                       const float* __restrict__ W_attn,
                       const float* __restrict__ b_attn,
                       float* __restrict__ u,
                       unsigned short* __restrict__ wpk) {
    const int tid = threadIdx.x;
    if (blockIdx.x < 32) {
        const int b = blockIdx.x;
        __shared__ float hrow[H];
        if (tid < H) hrow[tid] = hidden[b * H + tid];
        __syncthreads();
        if (tid < H) {
            const float* w = W_attn + (size_t)tid * (2 * H);
            float acc = b_attn[tid];
#pragma unroll
            for (int k = 0; k < H; ++k) acc = fmaf(w[k], hrow[k], acc);
            u[b * H + tid] = acc;
        }
    } else {
        const int idx  = (blockIdx.x - 32) * 256 + tid;   // 0..2047
        const int s    = idx >> 8;
        const int m    = (idx >> 6) & 3;
        const int lane = idx & 63;
        const int h    = m * 32 + (lane & 31);
        const int k0   = s * 16 + (lane >> 5) * 8;
        const float* src = W_attn + (size_t)h * (2 * H) + H + k0;
        const int base = ((s * 4 + m) * 64 + lane) * 8;
#pragma unroll
        for (int e = 0; e < 8; ++e) {
            const float x = src[e];
            const unsigned ux = fbits(x);
            const unsigned hb = ux & 0xffff0000u;         // truncated bf16 hi
            const float r = x - bfloat(hb);               // exact remainder
            wpk[base + e]         = (unsigned short)(ux >> 16);
            wpk[16384 + base + e] = (unsigned short)(fbits(r) >> 16);
        }
    }
}

// ---------------------------------------------------------------------------
// Kernel 2: scores via MFMA — RAGGED-AWARE staging (r19 optimum, 34.6 us).
//
// scores[b][t] only consumed for t < len_seq[b] (E[sum len] ~ B*T/2):
//  (a) per-row stage guard skips load+pack+LDS-write for masked rows
//      (column isolation keeps valid-region math bit-identical);
//  (b) strided tile assignment (tile = blk + 256q) spreads the masked
//      fraction evenly across blocks.
//
// Evidence ledger: pre-pack enc at stage time (r14 +22%), x-lo dropped
// (r17 +15%), hot loop = 1 ds_read_b128 + 2 MFMA /s-step, (512,2) +
// W2-in-regs (r15: (512,4) regresses), rotation swizzle (r9+), T14
// double-buffer (r11-r13 alternatives neutral), fused sm partials (r18),
// prep fusion regresses (r20).
// ---------------------------------------------------------------------------
__global__ __launch_bounds__(512, 2) void k_scores_mfma(
    const float* __restrict__ enc,                 // [T*B][H]
    const float* __restrict__ u,                   // [B][H]
    const float* __restrict__ v,                   // [H]
    const unsigned short* __restrict__ wpk,        // 64 KB frag-ordered hi|lo
    const int* __restrict__ len_seq,               // [B]
    float* __restrict__ scores,                    // [B][T]
    float* __restrict__ part)                      // [B][256] x (M,S)
{
    __shared__ uint2 hb[2][2048];                  // hi planes, 2 x 16 KB
    __shared__ float cbuf[2][2][4][32];            // [parity][tsel][mtile][b]
    __shared__ float pm[2][32], ps[2][32];         // partial fold buffers

    const int tid   = threadIdx.x;
    const int lane  = tid & 63;
    const int wid   = tid >> 6;     // 0..7
    const int tsel  = wid >> 2;     // 0..1 : which t of the tile
    const int mtile = wid & 3;      // 0..3 : 32-row h-tile
    const int l31   = lane & 31;
    const int kh    = lane >> 5;

    // staging role: 8 threads per tile-row, 4 float4 each
    const int srow = tid >> 3;      // tile row 0..63 (t-local = srow>>5, b = srow&31)
    const int st8  = tid & 7;

    const int blk = blockIdx.x;                 // strided tiles: tile(q) = blk + 256q
    const float4* enc4 = (const float4*)enc;    // 32 x 16B units per row

    // stage-guard constants: row's t for tile p = 2*(blk+256p) + (srow>>5)
    const int lenrow = len_seq[srow & 31];
    const int tsb    = 2 * blk + (srow >> 5);   // t of this row at p=0 (+512 per p)

    // ---- W2 fragments for this wave's mtile -> 64 VGPRs ----
    short8_t w2hi[8], w2lo[8];
#pragma unroll
    for (int s = 0; s < 8; ++s) {
        const int fo = ((s * 4 + mtile) * 64 + lane) * 8;   // ushort idx
        w2hi[s] = *(const short8_t*)(wpk + fo);
        w2lo[s] = *(const short8_t*)(wpk + 16384 + fo);
    }
    float4 uf[4], vv[4];
#pragma unroll
    for (int r4 = 0; r4 < 4; ++r4) {
        uf[r4] = *(const float4*)(u + l31 * H + mtile * 32 + r4 * 8 + kh * 4);
        vv[r4] = *(const float4*)(v + mtile * 32 + r4 * 8 + kh * 4);
    }
    const int lenb = len_seq[l31];              // used by flush threads

    // ---- prologue: tile 0 -> buf0 (guarded); issue tile-1 loads (guarded) ----
    float4 stg[4];
    {
        if (tsb < lenrow) {                     // tile 0 row valid
            const float4* gs = enc4 + ((size_t)(2 * blk) * 32 + srow) * 32;
#pragma unroll
            for (int i = 0; i < 4; ++i) stg[i] = gs[st8 + 8 * i];
#pragma unroll
            for (int i = 0; i < 4; ++i) {
                unsigned hi0, hi1;
                pack4hi(stg[i], hi0, hi1);
                const int p16 = st8 + 8 * i;
                const int idx = srow * 32 + (((p16 >> 1) + srow) & 15) * 2 + (p16 & 1);
                hb[0][idx] = make_uint2(hi0, hi1);
            }
        }
        if (tsb + 512 < lenrow) {               // tile 1 row valid
            const float4* gs1 = enc4 + ((size_t)(2 * (blk + 256)) * 32 + srow) * 32;
#pragma unroll
            for (int i = 0; i < 4; ++i) stg[i] = gs1[st8 + 8 * i];
        }
    }
    __syncthreads();   // buf0 ready

    const int rrow  = tsel * 32 + l31;          // reader's tile row
    const int rbase = rrow * 32;                // uint2 base of that row

    float m_run = -1e30f, s_run = 0.0f;         // online softmax partial

#pragma unroll 1
    for (int q = 0; q < 16; ++q) {
        const int cur = q & 1, nxt = cur ^ 1;

        // ---- pack+write tile q+1 (in stg) into buf[nxt]; guard matches the
        //      load guard that filled stg (same formula, p = q+1) ----
        if (q < 15 && tsb + 512 * (q + 1) < lenrow) {
#pragma unroll
            for (int i = 0; i < 4; ++i) {
                unsigned hi0, hi1;
                pack4hi(stg[i], hi0, hi1);
                const int p16 = st8 + 8 * i;
                const int idx = srow * 32 + (((p16 >> 1) + srow) & 15) * 2 + (p16 & 1);
                hb[nxt][idx] = make_uint2(hi0, hi1);
            }
        }
        // ---- issue tile q+2 loads (guarded; latency hides under compute) ----
        if (q < 14 && tsb + 512 * (q + 2) < lenrow) {
            const float4* gs = enc4 + ((size_t)(2 * (blk + 256 * (q + 2))) * 32 + srow) * 32;
#pragma unroll
            for (int i = 0; i < 4; ++i) stg[i] = gs[st8 + 8 * i];
        }

        // ---- compute own (t, mtile) from buf[cur]: 1 ds_read + 2 MFMA /s ----
        f32x16 acc;
#pragma unroll
        for (int r4 = 0; r4 < 4; ++r4) {
            acc[4 * r4 + 0] = uf[r4].x; acc[4 * r4 + 1] = uf[r4].y;
            acc[4 * r4 + 2] = uf[r4].z; acc[4 * r4 + 3] = uf[r4].w;
        }

#pragma unroll
        for (int s = 0; s < 8; ++s) {
            const int slot = (2 * s + kh + l31) & 15;       // (unit+row)&15
            const short8_t bh = *(const short8_t*)&hb[cur][rbase + slot * 2];
            acc = __builtin_amdgcn_mfma_f32_32x32x16_bf16(w2hi[s], bh, acc, 0, 0, 0);
            acc = __builtin_amdgcn_mfma_f32_32x32x16_bf16(w2lo[s], bh, acc, 0, 0, 0);
        }

        // ---- partial score over this wave's 32 h-rows ----
        float psum = 0.f;
#pragma unroll
        for (int r4 = 0; r4 < 4; ++r4) {
            psum = fmaf(fmaxf(acc[4 * r4 + 0], 0.f), vv[r4].x, psum);
            psum = fmaf(fmaxf(acc[4 * r4 + 1], 0.f), vv[r4].y, psum);
            psum = fmaf(fmaxf(acc[4 * r4 + 2], 0.f), vv[r4].z, psum);
            psum = fmaf(fmaxf(acc[4 * r4 + 3], 0.f), vv[r4].w, psum);
        }
        psum += __shfl_xor(psum, 32);   // collapse kh halves; lanes<32 hold b

        if (lane < 32) cbuf[cur][tsel][mtile][l31] = psum;

        __syncthreads();   // buf[nxt] written, cbuf[cur] visible, buf[cur] free

        if (mtile == 0 && lane < 32) {
            const float r = cbuf[cur][tsel][0][l31] + cbuf[cur][tsel][1][l31]
                          + cbuf[cur][tsel][2][l31] + cbuf[cur][tsel][3][l31];
            const int t = 2 * (blk + 256 * q) + tsel;
            scores[(size_t)l31 * T + t] = r;
            if (t < lenb) {                    // online (max, exp-sum) update
                const float m_new = fmaxf(m_run, r);
                s_run = s_run * __expf(m_run - m_new) + __expf(r - m_new);
                m_run = m_new;
            }
        }
    }

    // ---- fold tsel halves, one (M,S) per (b, block) ----
    if (mtile == 0 && lane < 32) { pm[tsel][l31] = m_run; ps[tsel][l31] = s_run; }
    __syncthreads();
    if (tid < 32) {
        const float m0 = pm[0][tid], m1 = pm[1][tid];
        const float s0 = ps[0][tid], s1 = ps[1][tid];
        const float M = fmaxf(m0, m1);
        const float S = s0 * __expf(m0 - M) + s1 * __expf(m1 - M);
        *(float2*)&part[((size_t)tid * 256 + blk) * 2] = make_float2(M, S);
    }
}

// ---------------------------------------------------------------------------
// Kernel 3: wide softmax finish — fold 256 per-block partials per b, then
// rescale in place. 256 blocks (8 chunks x 32 b) x 256 threads x 4 elems.
// ---------------------------------------------------------------------------
__global__ __launch_bounds__(256) void k_sm_final(
    float* __restrict__ out,            // [B][T] raw scores -> probs
    const int* __restrict__ len_seq,
    const float* __restrict__ part)     // [B][256] x (M,S)
{
    const int b    = blockIdx.x >> 3;
    const int c    = blockIdx.x & 7;
    const int tid  = threadIdx.x;
    const int lane = tid & 63;
    const int wid  = tid >> 6;
    const int len  = len_seq[b];

    __shared__ float rm[4], rs[4];

    float2 p = *(const float2*)&part[((size_t)b * 256 + tid) * 2];
    float m = p.x, s = p.y;
#pragma unroll
    for (int off = 32; off >= 1; off >>= 1) {
        const float m2 = __shfl_xor(m, off);
        const float s2 = __shfl_xor(s, off);
        const float M = fmaxf(m, m2);
        s = s * __expf(m - M) + s2 * __expf(m2 - M);
        m = M;
    }
    if (lane == 0) { rm[wid] = m; rs[wid] = s; }
    __syncthreads();
    const float M = fmaxf(fmaxf(rm[0], rm[1]), fmaxf(rm[2], rm[3]));
    const float S = rs[0] * __expf(rm[0] - M) + rs[1] * __expf(rm[1] - M)
                  + rs[2] * __expf(rm[2] - M) + rs[3] * __expf(rm[3] - M);
    const float inv = 1.0f / S;

    float* srow = out + (size_t)b * T + c * 1024;
#pragma unroll
    for (int i = 0; i < 4; ++i) {
        const int tl = tid + i * 256;
        const int t  = c * 1024 + tl;
        const float x = srow[tl];
        srow[tl] = (t < len) ? __expf(x - M) * inv : 0.0f;
    }
}

// ---------------------------------------------------------------------------
extern "C" void kernel_launch(void* const* d_in, const int* in_sizes, int n_in,
                              void* d_out, int out_size, void* d_ws, size_t ws_size,
                              hipStream_t stream) {
    const float* hidden = (const float*)d_in[0];
    const float* enc    = (const float*)d_in[1];
    const int*   len    = (const int*)d_in[2];
    const float* W      = (const float*)d_in[3];
    const float* bb     = (const float*)d_in[4];
    const float* v      = (const float*)d_in[5];

    float* out  = (float*)d_out;
    float* u_ws = (float*)d_ws;                                     // 16 KB
    unsigned short* wpk = (unsigned short*)((char*)d_ws + WPK_OFF); // 64 KB
    float* part = (float*)((char*)d_ws + PART_OFF);                 // 64 KB

    k_prep<<<40, 256, 0, stream>>>(hidden, W, bb, u_ws, wpk);
    k_scores_mfma<<<256, 512, 0, stream>>>(enc, u_ws, v, wpk, len, out, part);
    k_sm_final<<<B * 8, 256, 0, stream>>>(out, len, part);
}